// Round 2
// baseline (338.368 us; speedup 1.0000x reference)
//
#include <hip/hip_runtime.h>

// B=256, NT=301, D=96, NSEG=50; linspace(1,301,51) -> segment s = rows [6s, 6s+6]
#define BB 256
#define NTT 301
#define DD 96
#define NSEG 50
#define NTRI (DD * (DD - 1) / 2)   // 4560
#define OUTD (DD + NTRI)           // 4656

// A_ij = 0.5 * sum_{t=1..5} (x_i[t] x_j[t+1] - x_i[t+1] x_j[t]),  x = s - s[0]
//      = sum_{u=1..6} c_u(i) * x_j[u]
// c_1=-x_i2/2, c_2=(x_i1-x_i3)/2, c_3=(x_i2-x_i4)/2, c_4=(x_i3-x_i5)/2,
// c_5=(x_i4-x_i6)/2, c_6=x_i5/2   (0.5 folded into the per-row coefficients)

__global__ __launch_bounds__(256)
void logsig_kernel(const float* __restrict__ inp, float* __restrict__ out) {
    const int bs = blockIdx.x;          // 0 .. B*NSEG-1
    const int b  = bs / NSEG;
    const int s  = bs % NSEG;

    __shared__ float seg[7 * DD];                       // raw segment rows
    __shared__ __align__(16) float xs[6 * DD];          // xs[(t-1)*DD + ch] = s[t]-s[0]

    const float* src = inp + ((size_t)b * NTT + (size_t)6 * s) * DD;
    for (int idx = threadIdx.x; idx < 7 * DD; idx += 256)
        seg[idx] = src[idx];
    __syncthreads();
    for (int idx = threadIdx.x; idx < 6 * DD; idx += 256) {
        const int ch = idx % DD;
        xs[idx] = seg[idx + DD] - seg[ch];
    }
    __syncthreads();

    float* o = out + (size_t)bs * OUTD;

    // lvl1 = s[6]-s[0] = x[6]
    if (threadIdx.x < DD)
        o[threadIdx.x] = xs[5 * DD + threadIdx.x];

    const int ty = threadIdx.x >> 3;    // 0..31 : row within 32-row i-tile
    const int tx = threadIdx.x & 7;     // 0..7  : which float4 group within 32-col j-tile

    #pragma unroll
    for (int ti = 0; ti < 3; ++ti) {
        const int i = 32 * ti + ty;     // 0..95
        const float x1 = xs[0 * DD + i];
        const float x2 = xs[1 * DD + i];
        const float x3 = xs[2 * DD + i];
        const float x4 = xs[3 * DD + i];
        const float x5 = xs[4 * DD + i];
        const float x6 = xs[5 * DD + i];
        const float c1 = -0.5f * x2;
        const float c2 = 0.5f * (x1 - x3);
        const float c3 = 0.5f * (x2 - x4);
        const float c4 = 0.5f * (x3 - x5);
        const float c5 = 0.5f * (x4 - x6);
        const float c6 = 0.5f * x5;
        // o[DD + i*(191-i)/2 + (j-i-1)] == orow[j]
        float* orow = o + DD + i * (2 * DD - 1 - i) / 2 - i - 1;

        #pragma unroll
        for (int tj = ti; tj < 3; ++tj) {
            const int j0 = 32 * tj + 4 * tx;
            if (j0 + 3 <= i) continue;  // whole group at/below diagonal

            float q1[4], q2[4], q3[4], q4[4], q5[4], q6[4];
            *(float4*)q1 = *(const float4*)&xs[0 * DD + j0];
            *(float4*)q2 = *(const float4*)&xs[1 * DD + j0];
            *(float4*)q3 = *(const float4*)&xs[2 * DD + j0];
            *(float4*)q4 = *(const float4*)&xs[3 * DD + j0];
            *(float4*)q5 = *(const float4*)&xs[4 * DD + j0];
            *(float4*)q6 = *(const float4*)&xs[5 * DD + j0];

            float r[4];
            #pragma unroll
            for (int e = 0; e < 4; ++e) {
                float acc = c1 * q1[e];
                acc = fmaf(c2, q2[e], acc);
                acc = fmaf(c3, q3[e], acc);
                acc = fmaf(c4, q4[e], acc);
                acc = fmaf(c5, q5[e], acc);
                acc = fmaf(c6, q6[e], acc);
                r[e] = acc;
            }
            #pragma unroll
            for (int e = 0; e < 4; ++e) {
                const int j = j0 + e;
                if (j > i) orow[j] = r[e];
            }
        }
    }
}

extern "C" void kernel_launch(void* const* d_in, const int* in_sizes, int n_in,
                              void* d_out, int out_size, void* d_ws, size_t ws_size,
                              hipStream_t stream) {
    const float* inp = (const float*)d_in[0];
    float* out = (float*)d_out;
    logsig_kernel<<<BB * NSEG, 256, 0, stream>>>(inp, out);
}